// Round 9
// baseline (2874.834 us; speedup 1.0000x reference)
//
#include <hip/hip_runtime.h>
#include <hip/hip_fp16.h>

// Attention: ctx,W = softmax(Q K^T / 32 + mask, padmask) @ V
// B=8, QL=KL=2048, D=1024, fp32 I/O. fp16 MFMA internally (no fp32 MFMA on CDNA4).
#define B_ 8
#define QL_ 2048
#define KL_ 2048
#define D_ 1024

typedef _Float16 f16x8 __attribute__((ext_vector_type(8)));
typedef _Float16 f16x4 __attribute__((ext_vector_type(4)));
typedef float f32x4 __attribute__((ext_vector_type(4)));

// ---------------------------------------------------------------- async 16B
__device__ __forceinline__ void async16(const void* g, void* l) {
  __builtin_amdgcn_global_load_lds(
      (const __attribute__((address_space(1))) unsigned int*)g,
      (__attribute__((address_space(3))) unsigned int*)l, 16, 0, 0);
}

// ---------------------------------------------------------------- fp32->fp16
// scale folded in: Qh = (half)(Q/32) so the scores GEMM emits S' = S/sqrt(D).
__global__ __launch_bounds__(256) void cvt_k(const float* __restrict__ X,
                                             _Float16* __restrict__ Xh,
                                             float scale) {
  const int i = blockIdx.x * 256 + threadIdx.x;  // one thread per 8 floats
  const float4* src = reinterpret_cast<const float4*>(X);
  float4 a = src[i * 2], b = src[i * 2 + 1];
  f16x8 h;
  h[0] = (_Float16)(a.x * scale); h[1] = (_Float16)(a.y * scale);
  h[2] = (_Float16)(a.z * scale); h[3] = (_Float16)(a.w * scale);
  h[4] = (_Float16)(b.x * scale); h[5] = (_Float16)(b.y * scale);
  h[6] = (_Float16)(b.z * scale); h[7] = (_Float16)(b.w * scale);
  reinterpret_cast<f16x8*>(Xh)[i] = h;
}

// ---------------------------------------------------------------- V transpose
__global__ __launch_bounds__(256) void vt_k(const float* __restrict__ V,
                                            _Float16* __restrict__ VT) {
  __shared__ float tile[32][33];
  const int k0 = blockIdx.x * 32, d0 = blockIdx.y * 32, b = blockIdx.z;
  const float* Vb = V + (size_t)b * KL_ * D_;
  _Float16* VTb = VT + (size_t)b * D_ * KL_;
  const int c = threadIdx.x & 31, r = threadIdx.x >> 5;
#pragma unroll
  for (int s = 0; s < 4; ++s)
    tile[r + s * 8][c] = Vb[(size_t)(k0 + r + s * 8) * D_ + d0 + c];
  __syncthreads();
#pragma unroll
  for (int s = 0; s < 4; ++s)
    VTb[(size_t)(d0 + r + s * 8) * KL_ + k0 + c] = (_Float16)tile[c][r + s * 8];
}

// ---------------------------------------------------------------- fast GEMM
// Rounds 5-7 verified counted-vmcnt ring-5 skeleton (0 bank conflicts),
// 256x256 tile, BK=32, 512 thr = 8 waves (2M x 4N), per-wave 128x64 out.
// NEW (r9): register-frag prefetch one iter ahead. Two named frag sets
// (parity-static). Iter t:
//   1. vmcnt(8)        tile t+1 landed (allow t+2,t+3 = 8 loads in flight)
//   2. s_barrier       publishes tile t+1 to all waves; also proves all
//                      waves' frag-reads of t-1 retired (their lgkmcnt(0)
//                      preceded their barrier)
//   3. stage(t+4)      overwrites slot of t-1 (readers drained, step 2)
//   4. lgkmcnt(0)      frags(t) ready (issued at iter t-1; near-free)
//   5. issue 12 ds_read_b128 of frags(t+1) into the OTHER set
//   6. 32 MFMA on frags(t)  -> LDS pipe drains reads UNDER the MFMA cluster
// Peeled tail: vmcnt(4), vmcnt(0), then MFMA-only final iter.
// Never vmcnt(0) in the main loop (T4). Epilogue pure stores.
// SCORES=true: S' = Qh.Kh^T stored fp16 (Nc=2048, Kc=1024);
// SCORES=false: ctx = W @ VT^T stored fp32 (Nc=1024, Kc=2048).
template <bool SCORES>
__global__ __launch_bounds__(512, 2) void fgemm_k(
    const _Float16* __restrict__ Ah, const _Float16* __restrict__ Bh,
    float* __restrict__ Cf, _Float16* __restrict__ Ch) {
  constexpr int Mc = 2048;
  constexpr int Nc = SCORES ? 2048 : 1024;
  constexpr int Kc = SCORES ? 1024 : 2048;
  constexpr int NIT = Kc / 32;  // 32 or 64; NIT-3 odd for both (parity fixed)
  constexpr int GX = Mc / 256, GY = Nc / 256;
  constexpr int CPX = B_ * GX * GY / 8;  // blocks per XCD chunk (exact)

  extern __shared__ char lds[];  // 5 slots x 32 KiB (A 16K + B 16K each)

  const int t = threadIdx.x;
  const int lane = t & 63;
  const int wid = t >> 6;               // 0..7
  const int wr = wid >> 2, wc = wid & 3;
  const int lo = lane & 15, hi = lane >> 4;

  // XCD-chunked swizzle (bijective: 8 | nwg): scores = 1 batch per XCD.
  const int id = blockIdx.x;
  const int swz = (id & 7) * CPX + (id >> 3);
  const int b = swz / (GX * GY);
  const int rem = swz % (GX * GY);
  const int m0 = (rem / GY) * 256, n0 = (rem % GY) * 256;

  const _Float16* Ab = Ah + (size_t)b * Mc * Kc;
  const _Float16* Bb = Bh + (size_t)b * Nc * Kc;

  // ---- staging: per wave 2 instrs/matrix, each 1 KiB = 16 rows x 64 B.
  size_t aoff[2], boff[2];
  int ldst[2];
#pragma unroll
  for (int j = 0; j < 2; ++j) {
    const int row = (wid * 2 + j) * 16 + (lane >> 2);  // 0..255
    const int ch = (lane & 3) ^ ((row >> 1) & 3);      // source 16B chunk
    aoff[j] = (size_t)(m0 + row) * Kc + ch * 8;
    boff[j] = (size_t)(n0 + row) * Kc + ch * 8;
    ldst[j] = (wid * 2 + j) * 1024;  // wave-uniform byte offset
  }

  auto stage = [&](int it, int slot) {
    char* base = lds + slot * 32768;
    const int kb = it * 32;
#pragma unroll
    for (int j = 0; j < 2; ++j) {
      async16(Ab + aoff[j] + kb, base + ldst[j]);
      async16(Bb + boff[j] + kb, base + 16384 + ldst[j]);
    }
  };

  f32x4 acc[8][4];
#pragma unroll
  for (int m = 0; m < 8; ++m)
#pragma unroll
    for (int n = 0; n < 4; ++n)
#pragma unroll
      for (int i = 0; i < 4; ++i) acc[m][n][i] = 0.0f;

  // fragment LDS byte offsets (row*64 + swizzled-chunk*16)
  int raf[8], rbf_[4];
#pragma unroll
  for (int m = 0; m < 8; ++m) {
    const int r = wr * 128 + m * 16 + lo;
    raf[m] = r * 64 + ((hi ^ ((r >> 1) & 3)) << 4);
  }
#pragma unroll
  for (int n = 0; n < 4; ++n) {
    const int r = wc * 64 + n * 16 + lo;
    rbf_[n] = r * 64 + ((hi ^ ((r >> 1) & 3)) << 4);
  }

  // two named frag sets; frags(t) lives in set (t&1)==0 ? A : B
  f16x8 afA[8], bfA[4], afB[8], bfB[4];

#define READ_FRAGS(afX, bfX, slot_)                                   \
  do {                                                                \
    const char* Ac_ = lds + (slot_) * 32768;                          \
    const char* Bc_ = Ac_ + 16384;                                    \
    _Pragma("unroll") for (int m = 0; m < 8; ++m) afX[m] =            \
        *reinterpret_cast<const f16x8*>(Ac_ + raf[m]);                \
    _Pragma("unroll") for (int n = 0; n < 4; ++n) bfX[n] =            \
        *reinterpret_cast<const f16x8*>(Bc_ + rbf_[n]);               \
  } while (0)

#define MFMA_SET(afX, bfX)                                            \
  do {                                                                \
    __builtin_amdgcn_s_setprio(1);                                    \
    _Pragma("unroll") for (int m = 0; m < 8; ++m)                     \
        _Pragma("unroll") for (int n = 0; n < 4; ++n) acc[m][n] =     \
            __builtin_amdgcn_mfma_f32_16x16x32_f16(afX[m], bfX[n],    \
                                                   acc[m][n], 0, 0, 0); \
    __builtin_amdgcn_s_setprio(0);                                    \
  } while (0)

  // prologue: stage tiles 0..3; read frags(0) into set A
  stage(0, 0);
  stage(1, 1);
  stage(2, 2);
  stage(3, 3);
  asm volatile("s_waitcnt vmcnt(12)" ::: "memory");  // tile 0 landed
  __builtin_amdgcn_sched_barrier(0);
  __builtin_amdgcn_s_barrier();
  READ_FRAGS(afA, bfA, 0);

  int ss = 4;  // next stage slot (ring of 5)
  for (int it = 0; it < NIT - 3; ++it) {
    asm volatile("s_waitcnt vmcnt(8)" ::: "memory");  // tile it+1 landed
    __builtin_amdgcn_sched_barrier(0);
    __builtin_amdgcn_s_barrier();
    if (it + 4 < NIT) {
      stage(it + 4, ss);
      if (++ss == 5) ss = 0;
    }
    asm volatile("s_waitcnt lgkmcnt(0)" ::: "memory");  // frags(it) ready
    __builtin_amdgcn_sched_barrier(0);
    const int rslot = (it + 1) % 5;
    if ((it & 1) == 0) {
      READ_FRAGS(afB, bfB, rslot);          // frags(it+1) -> B
      __builtin_amdgcn_sched_barrier(0);    // reads stay above MFMAs
      MFMA_SET(afA, bfA);                   // frags(it), LDS drains under
    } else {
      READ_FRAGS(afA, bfA, rslot);
      __builtin_amdgcn_sched_barrier(0);
      MFMA_SET(afB, bfB);
    }
  }
  // peeled it = NIT-3 (odd: consume B, read A)
  asm volatile("s_waitcnt vmcnt(4)" ::: "memory");  // tile NIT-2 landed
  __builtin_amdgcn_sched_barrier(0);
  __builtin_amdgcn_s_barrier();
  asm volatile("s_waitcnt lgkmcnt(0)" ::: "memory");
  __builtin_amdgcn_sched_barrier(0);
  READ_FRAGS(afA, bfA, (NIT - 2) % 5);
  __builtin_amdgcn_sched_barrier(0);
  MFMA_SET(afB, bfB);
  // peeled it = NIT-2 (even: consume A, read B)
  asm volatile("s_waitcnt vmcnt(0)" ::: "memory");  // tile NIT-1 landed
  __builtin_amdgcn_sched_barrier(0);
  __builtin_amdgcn_s_barrier();
  asm volatile("s_waitcnt lgkmcnt(0)" ::: "memory");
  __builtin_amdgcn_sched_barrier(0);
  READ_FRAGS(afB, bfB, (NIT - 1) % 5);
  __builtin_amdgcn_sched_barrier(0);
  MFMA_SET(afA, bfA);
  // final it = NIT-1 (odd: consume B)
  asm volatile("s_waitcnt lgkmcnt(0)" ::: "memory");
  __builtin_amdgcn_sched_barrier(0);
  MFMA_SET(afB, bfB);
#undef READ_FRAGS
#undef MFMA_SET

  // Epilogue: pure stores. C layout: col = lane&15, row = (lane>>4)*4 + i.
  if constexpr (SCORES) {
    _Float16* Cb = Ch + (size_t)b * Mc * Nc;  // S' fp16 into ctx region
#pragma unroll
    for (int n = 0; n < 4; ++n) {
      const int col = n0 + wc * 64 + n * 16 + lo;
#pragma unroll
      for (int m = 0; m < 8; ++m) {
        const int r0 = m0 + wr * 128 + m * 16 + hi * 4;
#pragma unroll
        for (int i = 0; i < 4; ++i)
          Cb[(size_t)(r0 + i) * Nc + col] = (_Float16)acc[m][n][i];
      }
    }
  } else {
    float* Cb = Cf + (size_t)b * Mc * Nc;
#pragma unroll
    for (int n = 0; n < 4; ++n) {
      const int col = n0 + wc * 64 + n * 16 + lo;
#pragma unroll
      for (int m = 0; m < 8; ++m) {
        const int r0 = m0 + wr * 128 + m * 16 + hi * 4;
#pragma unroll
        for (int i = 0; i < 4; ++i)
          Cb[(size_t)(r0 + i) * Nc + col] = acc[m][n][i];
      }
    }
  }
}

// ---------------------------------------------------------------- row softmax
// One wave per row: read S' fp16 (already scaled by 1/sqrt(D)), add attn_mask,
// pad fill -1e12, exact softmax, write W fp32 + Wh fp16. Masked -> exp == 0
// (matches jax); all-masked row -> uniform 1/2048 (matches jax).
__global__ __launch_bounds__(256) void softmax_k(
    const _Float16* __restrict__ Sh, float* __restrict__ W,
    _Float16* __restrict__ Wh, const float* __restrict__ mask,
    const int* __restrict__ pad) {
  const int row = blockIdx.x * 4 + (threadIdx.x >> 6);
  const int lane = threadIdx.x & 63;
  const int b = row >> 11, q = row & 2047;
  const f16x4* Sr = reinterpret_cast<const f16x4*>(Sh + (size_t)row * KL_);
  float4* Wr = reinterpret_cast<float4*>(W + (size_t)row * KL_);
  const float4* Mr = reinterpret_cast<const float4*>(mask + (size_t)q * KL_);
  const int4* Pr = reinterpret_cast<const int4*>(pad + (size_t)b * KL_);
  float4 v[8];
#pragma unroll
  for (int s = 0; s < 8; ++s) {
    f16x4 sv = Sr[s * 64 + lane];
    float4 mk = Mr[s * 64 + lane];
    int4 p = Pr[s * 64 + lane];
    float4 x;
    x.x = p.x ? -1e12f : (float)sv[0] + mk.x;
    x.y = p.y ? -1e12f : (float)sv[1] + mk.y;
    x.z = p.z ? -1e12f : (float)sv[2] + mk.z;
    x.w = p.w ? -1e12f : (float)sv[3] + mk.w;
    v[s] = x;
  }
  float mx = -3.402823466e38f;
#pragma unroll
  for (int s = 0; s < 8; ++s)
    mx = fmaxf(mx, fmaxf(fmaxf(v[s].x, v[s].y), fmaxf(v[s].z, v[s].w)));
#pragma unroll
  for (int off = 32; off > 0; off >>= 1) mx = fmaxf(mx, __shfl_xor(mx, off));
  float sum = 0.0f;
#pragma unroll
  for (int s = 0; s < 8; ++s) {
    v[s].x = __expf(v[s].x - mx);
    v[s].y = __expf(v[s].y - mx);
    v[s].z = __expf(v[s].z - mx);
    v[s].w = __expf(v[s].w - mx);
    sum += v[s].x + v[s].y + v[s].z + v[s].w;
  }
#pragma unroll
  for (int off = 32; off > 0; off >>= 1) sum += __shfl_xor(sum, off);
  const float inv = 1.0f / sum;
  f16x4* Whr = reinterpret_cast<f16x4*>(Wh + (size_t)row * KL_);
#pragma unroll
  for (int s = 0; s < 8; ++s) {
    float4 o;
    o.x = v[s].x * inv;
    o.y = v[s].y * inv;
    o.z = v[s].z * inv;
    o.w = v[s].w * inv;
    Wr[s * 64 + lane] = o;
    f16x4 h;
    h[0] = (_Float16)o.x;
    h[1] = (_Float16)o.y;
    h[2] = (_Float16)o.z;
    h[3] = (_Float16)o.w;
    Whr[s * 64 + lane] = h;
  }
}

// ---------------------------------------------------------------- launch
extern "C" void kernel_launch(void* const* d_in, const int* in_sizes, int n_in,
                              void* d_out, int out_size, void* d_ws,
                              size_t ws_size, hipStream_t stream) {
  const float* Q = (const float*)d_in[0];
  const float* K = (const float*)d_in[1];
  const float* V = (const float*)d_in[2];
  const float* mask = (const float*)d_in[3];
  const int* pad = (const int*)d_in[4];

  float* ctx = (float*)d_out;              // [8][2048][1024] fp32 (final)
  float* W = ctx + (size_t)B_ * QL_ * D_;  // [8][2048][2048] fp32 (final)
  // S' fp16 scratch: EXACTLY the ctx region (64 MiB). Dead until PV runs;
  // strict stream order (scores -> softmax -> PV) makes the reuse safe.
  _Float16* Sh = (_Float16*)d_out;

  const size_t MB = 1024 * 1024;
  // d_ws layout (>= 96 MiB, confirmed rounds 2-8):
  _Float16* VT = (_Float16*)d_ws;                     // [8][1024][2048] 32 MiB
  _Float16* Qh = (_Float16*)((char*)d_ws + 32 * MB);  // 32 MiB
  _Float16* Kh = (_Float16*)((char*)d_ws + 64 * MB);  // 32 MiB
  _Float16* Wh = Qh;                                  // 64 MiB, reused post-QK

  // opt-in to 160 KiB dynamic LDS (idempotent, non-stream API)
  (void)hipFuncSetAttribute((const void*)fgemm_k<true>,
                            hipFuncAttributeMaxDynamicSharedMemorySize, 163840);
  (void)hipFuncSetAttribute((const void*)fgemm_k<false>,
                            hipFuncAttributeMaxDynamicSharedMemorySize, 163840);

  cvt_k<<<dim3(B_ * QL_ * D_ / 8 / 256), 256, 0, stream>>>(Q, Qh, 0.03125f);
  cvt_k<<<dim3(B_ * KL_ * D_ / 8 / 256), 256, 0, stream>>>(K, Kh, 1.0f);
  vt_k<<<dim3(KL_ / 32, D_ / 32, B_), 256, 0, stream>>>(V, VT);
  fgemm_k<true><<<dim3(B_ * 8 * 8), 512, 163840, stream>>>(Qh, Kh, nullptr, Sh);
  softmax_k<<<dim3(B_ * QL_ / 4), 256, 0, stream>>>(Sh, W, Wh, mask, pad);
  fgemm_k<false><<<dim3(B_ * 8 * 4), 512, 163840, stream>>>(Wh, VT, ctx,
                                                            nullptr);
}

// Round 10
// 280.573 us; speedup vs baseline: 10.2463x; 10.2463x over previous
//
#include <hip/hip_runtime.h>
#include <hip/hip_fp16.h>

// Attention: ctx,W = softmax(Q K^T / 32 + mask, padmask) @ V
// B=8, QL=KL=2048, D=1024, fp32 I/O. fp16 MFMA internally (no fp32 MFMA on CDNA4).
#define B_ 8
#define QL_ 2048
#define KL_ 2048
#define D_ 1024

typedef _Float16 f16x8 __attribute__((ext_vector_type(8)));
typedef _Float16 f16x4 __attribute__((ext_vector_type(4)));
typedef float f32x4 __attribute__((ext_vector_type(4)));

// ---------------------------------------------------------------- async 16B
__device__ __forceinline__ void async16(const void* g, void* l) {
  __builtin_amdgcn_global_load_lds(
      (const __attribute__((address_space(1))) unsigned int*)g,
      (__attribute__((address_space(3))) unsigned int*)l, 16, 0, 0);
}

// ---------------------------------------------------------------- fp32->fp16
// One launch converts BOTH Q (scaled by 1/32, so scores GEMM emits S' =
// S/sqrt(D) directly) and K (scale 1.0). Block range selects the tensor.
__global__ __launch_bounds__(256) void cvt2_k(const float* __restrict__ Q,
                                              const float* __restrict__ K,
                                              _Float16* __restrict__ Qh,
                                              _Float16* __restrict__ Kh) {
  constexpr int HALF = B_ * QL_ * D_ / 8 / 256;  // blocks per tensor
  const bool isQ = blockIdx.x < HALF;
  const int i = (isQ ? blockIdx.x : blockIdx.x - HALF) * 256 + threadIdx.x;
  const float4* src = reinterpret_cast<const float4*>(isQ ? Q : K);
  const float scale = isQ ? 0.03125f : 1.0f;
  float4 a = src[i * 2], b = src[i * 2 + 1];
  f16x8 h;
  h[0] = (_Float16)(a.x * scale); h[1] = (_Float16)(a.y * scale);
  h[2] = (_Float16)(a.z * scale); h[3] = (_Float16)(a.w * scale);
  h[4] = (_Float16)(b.x * scale); h[5] = (_Float16)(b.y * scale);
  h[6] = (_Float16)(b.z * scale); h[7] = (_Float16)(b.w * scale);
  reinterpret_cast<f16x8*>(isQ ? Qh : Kh)[i] = h;
}

// ---------------------------------------------------------------- V transpose
__global__ __launch_bounds__(256) void vt_k(const float* __restrict__ V,
                                            _Float16* __restrict__ VT) {
  __shared__ float tile[32][33];
  const int k0 = blockIdx.x * 32, d0 = blockIdx.y * 32, b = blockIdx.z;
  const float* Vb = V + (size_t)b * KL_ * D_;
  _Float16* VTb = VT + (size_t)b * D_ * KL_;
  const int c = threadIdx.x & 31, r = threadIdx.x >> 5;
#pragma unroll
  for (int s = 0; s < 4; ++s)
    tile[r + s * 8][c] = Vb[(size_t)(k0 + r + s * 8) * D_ + d0 + c];
  __syncthreads();
#pragma unroll
  for (int s = 0; s < 4; ++s)
    VTb[(size_t)(d0 + r + s * 8) * KL_ + k0 + c] = (_Float16)tile[c][r + s * 8];
}

// ---------------------------------------------------------------- fast GEMM
// Round-7 verified kernel (best: 284 us total). Counted-vmcnt ring-5
// skeleton, 256x256 tile, BK=32, 512 thr = 8 waves (2M x 4N), per-wave
// 128x64 out = 32 MFMA 16x16x32_f16 per K-step, 12 ds_read_b128/iter
// (compiler emits its own counted lgkmcnt per MFMA operand -> within-wave
// read/MFMA overlap already happens; R8/R9 grafts that tried to "improve"
// this regressed -- do not re-add phase barriers or frag double-buffering:
// unified VGPR/AGPR file cannot hold 2 frag sets + 128-reg acc).
// Ring-5 LDS (5 slots x 32 KiB = 160 KiB dynamic), prefetch distance 4:
//   iter t: waitcnt vmcnt(12) lgkmcnt(0) -> tile t landed; own reads of
//           t-1 done;  s_barrier -> all waves' t-stages landed, all waves'
//           reads of t-1 drained;  stage(t+4 -> slot of t-1);  compute(t).
//   peeled: vmcnt(8), vmcnt(4), vmcnt(0) for the last three tiles.
// Never vmcnt(0) in the main loop (T4). Epilogue pure stores.
// SCORES=true: S' = Qh.Kh^T stored fp16 (Nc=2048, Kc=1024);
// SCORES=false: ctx = W @ VT^T stored fp32 (Nc=1024, Kc=2048).
template <bool SCORES>
__global__ __launch_bounds__(512, 2) void fgemm_k(
    const _Float16* __restrict__ Ah, const _Float16* __restrict__ Bh,
    float* __restrict__ Cf, _Float16* __restrict__ Ch) {
  constexpr int Mc = 2048;
  constexpr int Nc = SCORES ? 2048 : 1024;
  constexpr int Kc = SCORES ? 1024 : 2048;
  constexpr int NIT = Kc / 32;
  constexpr int GX = Mc / 256, GY = Nc / 256;
  constexpr int CPX = B_ * GX * GY / 8;  // blocks per XCD chunk (exact)

  extern __shared__ char lds[];  // 5 slots x 32 KiB (A 16K + B 16K each)

  const int t = threadIdx.x;
  const int lane = t & 63;
  const int wid = t >> 6;               // 0..7
  const int wr = wid >> 2, wc = wid & 3;
  const int lo = lane & 15, hi = lane >> 4;

  // XCD-chunked swizzle (bijective: 8 | nwg): scores = 1 batch per XCD.
  const int id = blockIdx.x;
  const int swz = (id & 7) * CPX + (id >> 3);
  const int b = swz / (GX * GY);
  const int rem = swz % (GX * GY);
  const int m0 = (rem / GY) * 256, n0 = (rem % GY) * 256;

  const _Float16* Ab = Ah + (size_t)b * Mc * Kc;
  const _Float16* Bb = Bh + (size_t)b * Nc * Kc;

  // ---- staging: per wave 2 instrs/matrix, each 1 KiB = 16 rows x 64 B.
  // LDS dest wave-uniform (+lane*16 by HW); global source pre-swizzled.
  size_t aoff[2], boff[2];
  int ldst[2];
#pragma unroll
  for (int j = 0; j < 2; ++j) {
    const int row = (wid * 2 + j) * 16 + (lane >> 2);  // 0..255
    const int ch = (lane & 3) ^ ((row >> 1) & 3);      // source 16B chunk
    aoff[j] = (size_t)(m0 + row) * Kc + ch * 8;
    boff[j] = (size_t)(n0 + row) * Kc + ch * 8;
    ldst[j] = (wid * 2 + j) * 1024;  // wave-uniform byte offset
  }

  auto stage = [&](int it, int slot) {
    char* base = lds + slot * 32768;
    const int kb = it * 32;
#pragma unroll
    for (int j = 0; j < 2; ++j) {
      async16(Ab + aoff[j] + kb, base + ldst[j]);
      async16(Bb + boff[j] + kb, base + 16384 + ldst[j]);
    }
  };

  f32x4 acc[8][4];
#pragma unroll
  for (int m = 0; m < 8; ++m)
#pragma unroll
    for (int n = 0; n < 4; ++n)
#pragma unroll
      for (int i = 0; i < 4; ++i) acc[m][n][i] = 0.0f;

  // fragment LDS byte offsets (row*64 + swizzled-chunk*16)
  int raf[8], rbf_[4];
#pragma unroll
  for (int m = 0; m < 8; ++m) {
    const int r = wr * 128 + m * 16 + lo;
    raf[m] = r * 64 + ((hi ^ ((r >> 1) & 3)) << 4);
  }
#pragma unroll
  for (int n = 0; n < 4; ++n) {
    const int r = wc * 64 + n * 16 + lo;
    rbf_[n] = r * 64 + ((hi ^ ((r >> 1) & 3)) << 4);
  }

  auto compute = [&](int slot) {
    const char* Ac = lds + slot * 32768;
    const char* Bc = Ac + 16384;
    f16x8 af[8], bfr[4];
#pragma unroll
    for (int m = 0; m < 8; ++m)
      af[m] = *reinterpret_cast<const f16x8*>(Ac + raf[m]);
#pragma unroll
    for (int n = 0; n < 4; ++n)
      bfr[n] = *reinterpret_cast<const f16x8*>(Bc + rbf_[n]);
    __builtin_amdgcn_s_setprio(1);
#pragma unroll
    for (int m = 0; m < 8; ++m)
#pragma unroll
      for (int n = 0; n < 4; ++n)
        acc[m][n] = __builtin_amdgcn_mfma_f32_16x16x32_f16(af[m], bfr[n],
                                                           acc[m][n], 0, 0, 0);
    __builtin_amdgcn_s_setprio(0);
  };

  stage(0, 0);
  stage(1, 1);
  stage(2, 2);
  stage(3, 3);

  int cs = 0, ss = 4;  // compute slot, stage slot (ring of 5)
  for (int it = 0; it < NIT - 3; ++it) {
    asm volatile("s_waitcnt vmcnt(12) lgkmcnt(0)" ::: "memory");
    __builtin_amdgcn_sched_barrier(0);
    __builtin_amdgcn_s_barrier();
    if (it + 4 < NIT) {
      stage(it + 4, ss);
      if (++ss == 5) ss = 0;
    }
    compute(cs);
    if (++cs == 5) cs = 0;
  }
  asm volatile("s_waitcnt vmcnt(8) lgkmcnt(0)" ::: "memory");
  __builtin_amdgcn_sched_barrier(0);
  __builtin_amdgcn_s_barrier();
  compute(cs);
  if (++cs == 5) cs = 0;
  asm volatile("s_waitcnt vmcnt(4) lgkmcnt(0)" ::: "memory");
  __builtin_amdgcn_sched_barrier(0);
  __builtin_amdgcn_s_barrier();
  compute(cs);
  if (++cs == 5) cs = 0;
  asm volatile("s_waitcnt vmcnt(0) lgkmcnt(0)" ::: "memory");
  __builtin_amdgcn_sched_barrier(0);
  __builtin_amdgcn_s_barrier();
  compute(cs);

  // Epilogue: pure stores. C layout: col = lane&15, row = (lane>>4)*4 + i.
  if constexpr (SCORES) {
    _Float16* Cb = Ch + (size_t)b * Mc * Nc;  // S' fp16 into ctx region
#pragma unroll
    for (int n = 0; n < 4; ++n) {
      const int col = n0 + wc * 64 + n * 16 + lo;
#pragma unroll
      for (int m = 0; m < 8; ++m) {
        const int r0 = m0 + wr * 128 + m * 16 + hi * 4;
#pragma unroll
        for (int i = 0; i < 4; ++i)
          Cb[(size_t)(r0 + i) * Nc + col] = (_Float16)acc[m][n][i];
      }
    }
  } else {
    float* Cb = Cf + (size_t)b * Mc * Nc;
#pragma unroll
    for (int n = 0; n < 4; ++n) {
      const int col = n0 + wc * 64 + n * 16 + lo;
#pragma unroll
      for (int m = 0; m < 8; ++m) {
        const int r0 = m0 + wr * 128 + m * 16 + hi * 4;
#pragma unroll
        for (int i = 0; i < 4; ++i)
          Cb[(size_t)(r0 + i) * Nc + col] = acc[m][n][i];
      }
    }
  }
}

// ---------------------------------------------------------------- row softmax
// One wave per row: read S' fp16 (already scaled by 1/sqrt(D)), add attn_mask,
// pad fill -1e12, exact softmax, write W fp32 + Wh fp16. Masked -> exp == 0
// (matches jax); all-masked row -> uniform 1/2048 (matches jax).
__global__ __launch_bounds__(256) void softmax_k(
    const _Float16* __restrict__ Sh, float* __restrict__ W,
    _Float16* __restrict__ Wh, const float* __restrict__ mask,
    const int* __restrict__ pad) {
  const int row = blockIdx.x * 4 + (threadIdx.x >> 6);
  const int lane = threadIdx.x & 63;
  const int b = row >> 11, q = row & 2047;
  const f16x4* Sr = reinterpret_cast<const f16x4*>(Sh + (size_t)row * KL_);
  float4* Wr = reinterpret_cast<float4*>(W + (size_t)row * KL_);
  const float4* Mr = reinterpret_cast<const float4*>(mask + (size_t)q * KL_);
  const int4* Pr = reinterpret_cast<const int4*>(pad + (size_t)b * KL_);
  float4 v[8];
#pragma unroll
  for (int s = 0; s < 8; ++s) {
    f16x4 sv = Sr[s * 64 + lane];
    float4 mk = Mr[s * 64 + lane];
    int4 p = Pr[s * 64 + lane];
    float4 x;
    x.x = p.x ? -1e12f : (float)sv[0] + mk.x;
    x.y = p.y ? -1e12f : (float)sv[1] + mk.y;
    x.z = p.z ? -1e12f : (float)sv[2] + mk.z;
    x.w = p.w ? -1e12f : (float)sv[3] + mk.w;
    v[s] = x;
  }
  float mx = -3.402823466e38f;
#pragma unroll
  for (int s = 0; s < 8; ++s)
    mx = fmaxf(mx, fmaxf(fmaxf(v[s].x, v[s].y), fmaxf(v[s].z, v[s].w)));
#pragma unroll
  for (int off = 32; off > 0; off >>= 1) mx = fmaxf(mx, __shfl_xor(mx, off));
  float sum = 0.0f;
#pragma unroll
  for (int s = 0; s < 8; ++s) {
    v[s].x = __expf(v[s].x - mx);
    v[s].y = __expf(v[s].y - mx);
    v[s].z = __expf(v[s].z - mx);
    v[s].w = __expf(v[s].w - mx);
    sum += v[s].x + v[s].y + v[s].z + v[s].w;
  }
#pragma unroll
  for (int off = 32; off > 0; off >>= 1) sum += __shfl_xor(sum, off);
  const float inv = 1.0f / sum;
  f16x4* Whr = reinterpret_cast<f16x4*>(Wh + (size_t)row * KL_);
#pragma unroll
  for (int s = 0; s < 8; ++s) {
    float4 o;
    o.x = v[s].x * inv;
    o.y = v[s].y * inv;
    o.z = v[s].z * inv;
    o.w = v[s].w * inv;
    Wr[s * 64 + lane] = o;
    f16x4 h;
    h[0] = (_Float16)o.x;
    h[1] = (_Float16)o.y;
    h[2] = (_Float16)o.z;
    h[3] = (_Float16)o.w;
    Whr[s * 64 + lane] = h;
  }
}

// ---------------------------------------------------------------- launch
extern "C" void kernel_launch(void* const* d_in, const int* in_sizes, int n_in,
                              void* d_out, int out_size, void* d_ws,
                              size_t ws_size, hipStream_t stream) {
  const float* Q = (const float*)d_in[0];
  const float* K = (const float*)d_in[1];
  const float* V = (const float*)d_in[2];
  const float* mask = (const float*)d_in[3];
  const int* pad = (const int*)d_in[4];

  float* ctx = (float*)d_out;              // [8][2048][1024] fp32 (final)
  float* W = ctx + (size_t)B_ * QL_ * D_;  // [8][2048][2048] fp32 (final)
  // S' fp16 scratch: EXACTLY the ctx region (64 MiB). Dead until PV runs;
  // strict stream order (scores -> softmax -> PV) makes the reuse safe.
  _Float16* Sh = (_Float16*)d_out;

  const size_t MB = 1024 * 1024;
  // d_ws layout (>= 96 MiB, confirmed rounds 2-9):
  _Float16* VT = (_Float16*)d_ws;                     // [8][1024][2048] 32 MiB
  _Float16* Qh = (_Float16*)((char*)d_ws + 32 * MB);  // 32 MiB
  _Float16* Kh = (_Float16*)((char*)d_ws + 64 * MB);  // 32 MiB
  _Float16* Wh = Qh;                                  // 64 MiB, reused post-QK

  // opt-in to 160 KiB dynamic LDS (idempotent, non-stream API)
  (void)hipFuncSetAttribute((const void*)fgemm_k<true>,
                            hipFuncAttributeMaxDynamicSharedMemorySize, 163840);
  (void)hipFuncSetAttribute((const void*)fgemm_k<false>,
                            hipFuncAttributeMaxDynamicSharedMemorySize, 163840);

  cvt2_k<<<dim3(2 * B_ * QL_ * D_ / 8 / 256), 256, 0, stream>>>(Q, K, Qh, Kh);
  vt_k<<<dim3(KL_ / 32, D_ / 32, B_), 256, 0, stream>>>(V, VT);
  fgemm_k<true><<<dim3(B_ * 8 * 8), 512, 163840, stream>>>(Qh, Kh, nullptr, Sh);
  softmax_k<<<dim3(B_ * QL_ / 4), 256, 0, stream>>>(Sh, W, Wh, mask, pad);
  fgemm_k<false><<<dim3(B_ * 8 * 4), 512, 163840, stream>>>(Wh, VT, ctx,
                                                            nullptr);
}

// Round 11
// 272.211 us; speedup vs baseline: 10.5611x; 1.0307x over previous
//
#include <hip/hip_runtime.h>
#include <hip/hip_fp16.h>

// Attention: ctx,W = softmax(Q K^T / 32 + mask, padmask) @ V
// B=8, QL=KL=2048, D=1024, fp32 I/O. fp16 MFMA internally (no fp32 MFMA on CDNA4).
#define B_ 8
#define QL_ 2048
#define KL_ 2048
#define D_ 1024

typedef _Float16 f16x8 __attribute__((ext_vector_type(8)));
typedef _Float16 f16x4 __attribute__((ext_vector_type(4)));
typedef float f32x4 __attribute__((ext_vector_type(4)));

// ---------------------------------------------------------------- async 16B
__device__ __forceinline__ void async16(const void* g, void* l) {
  __builtin_amdgcn_global_load_lds(
      (const __attribute__((address_space(1))) unsigned int*)g,
      (__attribute__((address_space(3))) unsigned int*)l, 16, 0, 0);
}

// ---------------------------------------------------------------- fp32->fp16
// One launch converts BOTH Q (scaled by 1/32, so scores GEMM emits S' =
// S/sqrt(D) directly) and K (scale 1.0). Block range selects the tensor.
__global__ __launch_bounds__(256) void cvt2_k(const float* __restrict__ Q,
                                              const float* __restrict__ K,
                                              _Float16* __restrict__ Qh,
                                              _Float16* __restrict__ Kh) {
  constexpr int HALF = B_ * QL_ * D_ / 8 / 256;  // blocks per tensor
  const bool isQ = blockIdx.x < HALF;
  const int i = (isQ ? blockIdx.x : blockIdx.x - HALF) * 256 + threadIdx.x;
  const float4* src = reinterpret_cast<const float4*>(isQ ? Q : K);
  const float scale = isQ ? 0.03125f : 1.0f;
  float4 a = src[i * 2], b = src[i * 2 + 1];
  f16x8 h;
  h[0] = (_Float16)(a.x * scale); h[1] = (_Float16)(a.y * scale);
  h[2] = (_Float16)(a.z * scale); h[3] = (_Float16)(a.w * scale);
  h[4] = (_Float16)(b.x * scale); h[5] = (_Float16)(b.y * scale);
  h[6] = (_Float16)(b.z * scale); h[7] = (_Float16)(b.w * scale);
  reinterpret_cast<f16x8*>(isQ ? Qh : Kh)[i] = h;
}

// ---------------------------------------------------------------- V transpose
__global__ __launch_bounds__(256) void vt_k(const float* __restrict__ V,
                                            _Float16* __restrict__ VT) {
  __shared__ float tile[32][33];
  const int k0 = blockIdx.x * 32, d0 = blockIdx.y * 32, b = blockIdx.z;
  const float* Vb = V + (size_t)b * KL_ * D_;
  _Float16* VTb = VT + (size_t)b * D_ * KL_;
  const int c = threadIdx.x & 31, r = threadIdx.x >> 5;
#pragma unroll
  for (int s = 0; s < 4; ++s)
    tile[r + s * 8][c] = Vb[(size_t)(k0 + r + s * 8) * D_ + d0 + c];
  __syncthreads();
#pragma unroll
  for (int s = 0; s < 4; ++s)
    VTb[(size_t)(d0 + r + s * 8) * KL_ + k0 + c] = (_Float16)tile[c][r + s * 8];
}

// ---------------------------------------------------------------- fast GEMM
// Verified ring skeleton (rounds 5-7/10 ledger), parameter change only:
// BK=64, ring-2 (2 slots x 64 KiB = 128 KiB) -> HALF the per-K-element
// barrier/stage/wait overhead. 256x256 tile, 512 thr = 8 waves (2M x 4N),
// per-wave 128x64 out = 64 MFMA 16x16x32_f16 + 24 ds_read_b128 per iter,
// split into two k-halves (sched_barrier between) to cap live VGPRs (~200
// < 256 cap; R9 lesson: never exceed the unified-file budget).
//   iter t: vmcnt(0) lgkmcnt(0)  // tile t landed (cover = 1 full iter
//           ~1700cyc >> 900cyc HBM latency; own reads of t-1 done)
//           s_barrier            // all waves: t visible, t-1 reads drained
//           stage(t+1 -> slot (t+1)&1)   // opposite slot, free per ledger
//           compute(slot t&1): kh0 {12 ds_read + 32 MFMA} | kh1 likewise
// LDS row = 128 B; swizzle chunk ^= row&7 over 8 chunks -> 8 accesses/bank
// per b128 wave-read = conflict-free minimum. kh=1 chunk = kh0 chunk ^ 4
// -> byte offset ^ 64 (register-free second-half addressing).
// SCORES=true: S' = Qh.Kh^T stored fp16 (Nc=2048, Kc=1024, NIT=16);
// SCORES=false: ctx = W @ VT^T stored fp32 (Nc=1024, Kc=2048, NIT=32).
template <bool SCORES>
__global__ __launch_bounds__(512, 2) void fgemm_k(
    const _Float16* __restrict__ Ah, const _Float16* __restrict__ Bh,
    float* __restrict__ Cf, _Float16* __restrict__ Ch) {
  constexpr int Mc = 2048;
  constexpr int Nc = SCORES ? 2048 : 1024;
  constexpr int Kc = SCORES ? 1024 : 2048;
  constexpr int NIT = Kc / 64;
  constexpr int GX = Mc / 256, GY = Nc / 256;
  constexpr int CPX = B_ * GX * GY / 8;  // blocks per XCD chunk (exact)

  extern __shared__ char lds[];  // 2 slots x 64 KiB (A 32K + B 32K each)

  const int t = threadIdx.x;
  const int lane = t & 63;
  const int wid = t >> 6;               // 0..7
  const int wr = wid >> 2, wc = wid & 3;
  const int lo = lane & 15, hi = lane >> 4;

  // XCD-chunked swizzle (bijective: 8 | nwg): scores = 1 batch per XCD.
  const int id = blockIdx.x;
  const int swz = (id & 7) * CPX + (id >> 3);
  const int b = swz / (GX * GY);
  const int rem = swz % (GX * GY);
  const int m0 = (rem / GY) * 256, n0 = (rem % GY) * 256;

  const _Float16* Ab = Ah + (size_t)b * Mc * Kc;
  const _Float16* Bb = Bh + (size_t)b * Nc * Kc;

  // ---- staging: 4 instrs/matrix/thread; instr j covers rows j*64..j*64+63.
  // LDS dest lane-linear (row = j*64 + wid*8 + lane>>3, chunk = lane&7);
  // global source pre-swizzled: stored chunk c holds global chunk c^(row&7),
  // and row&7 == lane>>3 here.
  int aoff[4], boff[4], ldst[4];
#pragma unroll
  for (int j = 0; j < 4; ++j) {
    const int row = j * 64 + wid * 8 + (lane >> 3);
    const int cg = (lane & 7) ^ (lane >> 3);  // source 16B chunk
    aoff[j] = (m0 + row) * Kc + cg * 8;
    boff[j] = (n0 + row) * Kc + cg * 8;
    ldst[j] = j * 8192 + wid * 1024;  // wave-uniform byte offset
  }

  auto stage = [&](int it, int slot) {
    char* base = lds + slot * 65536;
    const int kb = it * 64;
#pragma unroll
    for (int j = 0; j < 4; ++j) {
      async16(Ab + aoff[j] + kb, base + ldst[j]);
      async16(Bb + boff[j] + kb, base + 32768 + ldst[j]);
    }
  };

  f32x4 acc[8][4];
#pragma unroll
  for (int m = 0; m < 8; ++m)
#pragma unroll
    for (int n = 0; n < 4; ++n)
#pragma unroll
      for (int i = 0; i < 4; ++i) acc[m][n][i] = 0.0f;

  // fragment byte offsets for k-half 0 (row*128 + swizzled-chunk*16);
  // k-half 1 is offset ^ 64 (chunk bit2 flips under XOR with row&7).
  int raf[8], rbf_[4];
#pragma unroll
  for (int m = 0; m < 8; ++m) {
    const int r = wr * 128 + m * 16 + lo;
    raf[m] = r * 128 + ((hi ^ (r & 7)) << 4);
  }
#pragma unroll
  for (int n = 0; n < 4; ++n) {
    const int r = wc * 64 + n * 16 + lo;
    rbf_[n] = r * 128 + ((hi ^ (r & 7)) << 4);
  }

  auto compute = [&](int slot) {
    const char* Ac = lds + slot * 65536;
    const char* Bc = Ac + 32768;
#pragma unroll
    for (int kh = 0; kh < 2; ++kh) {
      const int kx = kh * 64;  // chunk ^4 -> byte ^64
      f16x8 af[8], bfr[4];
#pragma unroll
      for (int m = 0; m < 8; ++m)
        af[m] = *reinterpret_cast<const f16x8*>(Ac + (raf[m] ^ kx));
#pragma unroll
      for (int n = 0; n < 4; ++n)
        bfr[n] = *reinterpret_cast<const f16x8*>(Bc + (rbf_[n] ^ kx));
      __builtin_amdgcn_s_setprio(1);
#pragma unroll
      for (int m = 0; m < 8; ++m)
#pragma unroll
        for (int n = 0; n < 4; ++n)
          acc[m][n] = __builtin_amdgcn_mfma_f32_16x16x32_f16(
              af[m], bfr[n], acc[m][n], 0, 0, 0);
      __builtin_amdgcn_s_setprio(0);
      __builtin_amdgcn_sched_barrier(0);  // keep k-halves separate (VGPR cap)
    }
  };

  stage(0, 0);

  for (int it = 0; it < NIT; ++it) {
    asm volatile("s_waitcnt vmcnt(0) lgkmcnt(0)" ::: "memory");
    __builtin_amdgcn_sched_barrier(0);
    __builtin_amdgcn_s_barrier();
    if (it + 1 < NIT) stage(it + 1, (it + 1) & 1);
    compute(it & 1);
  }

  // Epilogue: pure stores. C layout: col = lane&15, row = (lane>>4)*4 + i.
  if constexpr (SCORES) {
    _Float16* Cb = Ch + (size_t)b * Mc * Nc;  // S' fp16 into ctx region
#pragma unroll
    for (int n = 0; n < 4; ++n) {
      const int col = n0 + wc * 64 + n * 16 + lo;
#pragma unroll
      for (int m = 0; m < 8; ++m) {
        const int r0 = m0 + wr * 128 + m * 16 + hi * 4;
#pragma unroll
        for (int i = 0; i < 4; ++i)
          Cb[(size_t)(r0 + i) * Nc + col] = (_Float16)acc[m][n][i];
      }
    }
  } else {
    float* Cb = Cf + (size_t)b * Mc * Nc;
#pragma unroll
    for (int n = 0; n < 4; ++n) {
      const int col = n0 + wc * 64 + n * 16 + lo;
#pragma unroll
      for (int m = 0; m < 8; ++m) {
        const int r0 = m0 + wr * 128 + m * 16 + hi * 4;
#pragma unroll
        for (int i = 0; i < 4; ++i)
          Cb[(size_t)(r0 + i) * Nc + col] = acc[m][n][i];
      }
    }
  }
}

// ---------------------------------------------------------------- row softmax
// One wave per row: read S' fp16 (already scaled by 1/sqrt(D)), add attn_mask,
// pad fill -1e12, exact softmax, write W fp32 + Wh fp16. Masked -> exp == 0
// (matches jax); all-masked row -> uniform 1/2048 (matches jax).
__global__ __launch_bounds__(256) void softmax_k(
    const _Float16* __restrict__ Sh, float* __restrict__ W,
    _Float16* __restrict__ Wh, const float* __restrict__ mask,
    const int* __restrict__ pad) {
  const int row = blockIdx.x * 4 + (threadIdx.x >> 6);
  const int lane = threadIdx.x & 63;
  const int b = row >> 11, q = row & 2047;
  const f16x4* Sr = reinterpret_cast<const f16x4*>(Sh + (size_t)row * KL_);
  float4* Wr = reinterpret_cast<float4*>(W + (size_t)row * KL_);
  const float4* Mr = reinterpret_cast<const float4*>(mask + (size_t)q * KL_);
  const int4* Pr = reinterpret_cast<const int4*>(pad + (size_t)b * KL_);
  float4 v[8];
#pragma unroll
  for (int s = 0; s < 8; ++s) {
    f16x4 sv = Sr[s * 64 + lane];
    float4 mk = Mr[s * 64 + lane];
    int4 p = Pr[s * 64 + lane];
    float4 x;
    x.x = p.x ? -1e12f : (float)sv[0] + mk.x;
    x.y = p.y ? -1e12f : (float)sv[1] + mk.y;
    x.z = p.z ? -1e12f : (float)sv[2] + mk.z;
    x.w = p.w ? -1e12f : (float)sv[3] + mk.w;
    v[s] = x;
  }
  float mx = -3.402823466e38f;
#pragma unroll
  for (int s = 0; s < 8; ++s)
    mx = fmaxf(mx, fmaxf(fmaxf(v[s].x, v[s].y), fmaxf(v[s].z, v[s].w)));
#pragma unroll
  for (int off = 32; off > 0; off >>= 1) mx = fmaxf(mx, __shfl_xor(mx, off));
  float sum = 0.0f;
#pragma unroll
  for (int s = 0; s < 8; ++s) {
    v[s].x = __expf(v[s].x - mx);
    v[s].y = __expf(v[s].y - mx);
    v[s].z = __expf(v[s].z - mx);
    v[s].w = __expf(v[s].w - mx);
    sum += v[s].x + v[s].y + v[s].z + v[s].w;
  }
#pragma unroll
  for (int off = 32; off > 0; off >>= 1) sum += __shfl_xor(sum, off);
  const float inv = 1.0f / sum;
  f16x4* Whr = reinterpret_cast<f16x4*>(Wh + (size_t)row * KL_);
#pragma unroll
  for (int s = 0; s < 8; ++s) {
    float4 o;
    o.x = v[s].x * inv;
    o.y = v[s].y * inv;
    o.z = v[s].z * inv;
    o.w = v[s].w * inv;
    Wr[s * 64 + lane] = o;
    f16x4 h;
    h[0] = (_Float16)o.x;
    h[1] = (_Float16)o.y;
    h[2] = (_Float16)o.z;
    h[3] = (_Float16)o.w;
    Whr[s * 64 + lane] = h;
  }
}

// ---------------------------------------------------------------- launch
extern "C" void kernel_launch(void* const* d_in, const int* in_sizes, int n_in,
                              void* d_out, int out_size, void* d_ws,
                              size_t ws_size, hipStream_t stream) {
  const float* Q = (const float*)d_in[0];
  const float* K = (const float*)d_in[1];
  const float* V = (const float*)d_in[2];
  const float* mask = (const float*)d_in[3];
  const int* pad = (const int*)d_in[4];

  float* ctx = (float*)d_out;              // [8][2048][1024] fp32 (final)
  float* W = ctx + (size_t)B_ * QL_ * D_;  // [8][2048][2048] fp32 (final)
  // S' fp16 scratch: EXACTLY the ctx region (64 MiB). Dead until PV runs;
  // strict stream order (scores -> softmax -> PV) makes the reuse safe.
  _Float16* Sh = (_Float16*)d_out;

  const size_t MB = 1024 * 1024;
  // d_ws layout (>= 96 MiB, confirmed rounds 2-10):
  _Float16* VT = (_Float16*)d_ws;                     // [8][1024][2048] 32 MiB
  _Float16* Qh = (_Float16*)((char*)d_ws + 32 * MB);  // 32 MiB
  _Float16* Kh = (_Float16*)((char*)d_ws + 64 * MB);  // 32 MiB
  _Float16* Wh = Qh;                                  // 64 MiB, reused post-QK

  // opt-in to 128 KiB dynamic LDS (idempotent, non-stream API)
  (void)hipFuncSetAttribute((const void*)fgemm_k<true>,
                            hipFuncAttributeMaxDynamicSharedMemorySize, 131072);
  (void)hipFuncSetAttribute((const void*)fgemm_k<false>,
                            hipFuncAttributeMaxDynamicSharedMemorySize, 131072);

  cvt2_k<<<dim3(2 * B_ * QL_ * D_ / 8 / 256), 256, 0, stream>>>(Q, K, Qh, Kh);
  vt_k<<<dim3(KL_ / 32, D_ / 32, B_), 256, 0, stream>>>(V, VT);
  fgemm_k<true><<<dim3(B_ * 8 * 8), 512, 131072, stream>>>(Qh, Kh, nullptr, Sh);
  softmax_k<<<dim3(B_ * QL_ / 4), 256, 0, stream>>>(Sh, W, Wh, mask, pad);
  fgemm_k<false><<<dim3(B_ * 8 * 4), 512, 131072, stream>>>(Wh, VT, ctx,
                                                            nullptr);
}

// Round 12
// 249.324 us; speedup vs baseline: 11.5305x; 1.0918x over previous
//
#include <hip/hip_runtime.h>
#include <hip/hip_fp16.h>

// Attention: ctx,W = softmax(Q K^T / 32 + mask, padmask) @ V
// B=8, QL=KL=2048, D=1024, fp32 I/O. fp16 MFMA internally (no fp32 MFMA on CDNA4).
// R12: PV K-compaction -- pad-masked keys have W == 0 exactly, so PV skips them.
#define B_ 8
#define QL_ 2048
#define KL_ 2048
#define D_ 1024

typedef _Float16 f16x8 __attribute__((ext_vector_type(8)));
typedef _Float16 f16x4 __attribute__((ext_vector_type(4)));
typedef float f32x4 __attribute__((ext_vector_type(4)));

// ---------------------------------------------------------------- async 16B
__device__ __forceinline__ void async16(const void* g, void* l) {
  __builtin_amdgcn_global_load_lds(
      (const __attribute__((address_space(1))) unsigned int*)g,
      (__attribute__((address_space(3))) unsigned int*)l, 16, 0, 0);
}

// ---------------------------------------------------------------- prefix scan
// Per batch: pos[b][k] = exclusive prefix count of kept (pad==0) keys;
// kcp[b] = total kept. kc==0 guard (prob ~0): identity mapping, kcp=2048.
__global__ __launch_bounds__(256) void prep_k(const int* __restrict__ pad,
                                              int* __restrict__ pos,
                                              int* __restrict__ kcp) {
  const int b = blockIdx.x;
  const int t = threadIdx.x;
  const int lane = t & 63, wv = t >> 6;
  __shared__ int wsum[4], wpre[4], kc_sh;
  const int* pr = pad + b * KL_;
  int* po = pos + b * KL_;
  int c[8], loc = 0;
#pragma unroll
  for (int j = 0; j < 8; ++j) {
    c[j] = (pr[t * 8 + j] == 0);
    loc += c[j];
  }
  int inc = loc;  // inclusive scan across the wave
  for (int d = 1; d < 64; d <<= 1) {
    int v = __shfl_up(inc, d);
    if (lane >= d) inc += v;
  }
  if (lane == 63) wsum[wv] = inc;
  __syncthreads();
  if (t == 0) {
    int acc = 0;
    for (int w = 0; w < 4; ++w) {
      wpre[w] = acc;
      acc += wsum[w];
    }
    kc_sh = acc;
    kcp[b] = (acc == 0) ? KL_ : acc;
  }
  __syncthreads();
  const int kc = kc_sh;
  int base = wpre[wv] + inc - loc;  // exclusive prefix for this thread
#pragma unroll
  for (int j = 0; j < 8; ++j) {
    po[t * 8 + j] = (kc == 0) ? (t * 8 + j) : base;
    base += c[j];
  }
}

// ---------------------------------------------------------------- fp32->fp16
// One launch converts BOTH Q (scaled by 1/32, so scores GEMM emits S' =
// S/sqrt(D) directly) and K (scale 1.0). Block range selects the tensor.
__global__ __launch_bounds__(256) void cvt2_k(const float* __restrict__ Q,
                                              const float* __restrict__ K,
                                              _Float16* __restrict__ Qh,
                                              _Float16* __restrict__ Kh) {
  constexpr int HALF = B_ * QL_ * D_ / 8 / 256;  // blocks per tensor
  const bool isQ = blockIdx.x < HALF;
  const int i = (isQ ? blockIdx.x : blockIdx.x - HALF) * 256 + threadIdx.x;
  const float4* src = reinterpret_cast<const float4*>(isQ ? Q : K);
  const float scale = isQ ? 0.03125f : 1.0f;
  float4 a = src[i * 2], b = src[i * 2 + 1];
  f16x8 h;
  h[0] = (_Float16)(a.x * scale); h[1] = (_Float16)(a.y * scale);
  h[2] = (_Float16)(a.z * scale); h[3] = (_Float16)(a.w * scale);
  h[4] = (_Float16)(b.x * scale); h[5] = (_Float16)(b.y * scale);
  h[6] = (_Float16)(b.z * scale); h[7] = (_Float16)(b.w * scale);
  reinterpret_cast<f16x8*>(isQ ? Qh : Kh)[i] = h;
}

// ------------------------------------------------- V transpose (dense + compact)
__global__ __launch_bounds__(256) void vt_k(const float* __restrict__ V,
                                            _Float16* __restrict__ VT) {
  __shared__ float tile[32][33];
  const int k0 = blockIdx.x * 32, d0 = blockIdx.y * 32, b = blockIdx.z;
  const float* Vb = V + (size_t)b * KL_ * D_;
  _Float16* VTb = VT + (size_t)b * D_ * KL_;
  const int c = threadIdx.x & 31, r = threadIdx.x >> 5;
#pragma unroll
  for (int s = 0; s < 4; ++s)
    tile[r + s * 8][c] = Vb[(size_t)(k0 + r + s * 8) * D_ + d0 + c];
  __syncthreads();
#pragma unroll
  for (int s = 0; s < 4; ++s)
    VTb[(size_t)(d0 + r + s * 8) * KL_ + k0 + c] = (_Float16)tile[c][r + s * 8];
}

// Compact variant: kept column k goes to packed position pos[b][k].
// Dropped/tail columns keep stale finite data -- PV multiplies them by the
// zeroed Whc tail, so 0 x finite == 0 (exact).
__global__ __launch_bounds__(256) void vtc_k(const float* __restrict__ V,
                                             _Float16* __restrict__ VTc,
                                             const int* __restrict__ pad,
                                             const int* __restrict__ pos) {
  __shared__ float tile[32][33];
  const int k0 = blockIdx.x * 32, d0 = blockIdx.y * 32, b = blockIdx.z;
  const float* Vb = V + (size_t)b * KL_ * D_;
  _Float16* VTb = VTc + (size_t)b * D_ * KL_;
  const int c = threadIdx.x & 31, r = threadIdx.x >> 5;
#pragma unroll
  for (int s = 0; s < 4; ++s)
    tile[r + s * 8][c] = Vb[(size_t)(k0 + r + s * 8) * D_ + d0 + c];
  __syncthreads();
  const int kk = k0 + c;
  const int keep = (pad[b * KL_ + kk] == 0);
  const int col = pos[b * KL_ + kk];
#pragma unroll
  for (int s = 0; s < 4; ++s)
    if (keep)
      VTb[(size_t)(d0 + r + s * 8) * KL_ + col] = (_Float16)tile[c][r + s * 8];
}

// ---------------------------------------------------------------- dense GEMM
// r11 verified: ring-2, BK=64, 256x256 tile, 512 thr = 8 waves (2M x 4N),
// per-wave 128x64 = 64 MFMA 16x16x32_f16 + 24 ds_read_b128 per iter, k-half
// split (VGPR cap), 0 bank conflicts, 1 barrier + 1 counted... vmcnt(0) wait
// per iter with full-iteration prefetch cover.
// SCORES=true: S' = Qh.Kh^T stored fp16 (Nc=2048, Kc=1024, NIT=16);
// SCORES=false: ctx = W @ VT^T stored fp32 (Nc=1024, Kc=2048, NIT=32).
template <bool SCORES>
__global__ __launch_bounds__(512, 2) void fgemm_k(
    const _Float16* __restrict__ Ah, const _Float16* __restrict__ Bh,
    float* __restrict__ Cf, _Float16* __restrict__ Ch) {
  constexpr int Mc = 2048;
  constexpr int Nc = SCORES ? 2048 : 1024;
  constexpr int Kc = SCORES ? 1024 : 2048;
  constexpr int NIT = Kc / 64;
  constexpr int GX = Mc / 256, GY = Nc / 256;
  constexpr int CPX = B_ * GX * GY / 8;

  extern __shared__ char lds[];  // 2 slots x 64 KiB

  const int t = threadIdx.x;
  const int lane = t & 63;
  const int wid = t >> 6;
  const int wr = wid >> 2, wc = wid & 3;
  const int lo = lane & 15, hi = lane >> 4;

  const int id = blockIdx.x;
  const int swz = (id & 7) * CPX + (id >> 3);
  const int b = swz / (GX * GY);
  const int rem = swz % (GX * GY);
  const int m0 = (rem / GY) * 256, n0 = (rem % GY) * 256;

  const _Float16* Ab = Ah + (size_t)b * Mc * Kc;
  const _Float16* Bb = Bh + (size_t)b * Nc * Kc;

  int aoff[4], boff[4], ldst[4];
#pragma unroll
  for (int j = 0; j < 4; ++j) {
    const int row = j * 64 + wid * 8 + (lane >> 3);
    const int cg = (lane & 7) ^ (lane >> 3);
    aoff[j] = (m0 + row) * Kc + cg * 8;
    boff[j] = (n0 + row) * Kc + cg * 8;
    ldst[j] = j * 8192 + wid * 1024;
  }

  auto stage = [&](int it, int slot) {
    char* base = lds + slot * 65536;
    const int kb = it * 64;
#pragma unroll
    for (int j = 0; j < 4; ++j) {
      async16(Ab + aoff[j] + kb, base + ldst[j]);
      async16(Bb + boff[j] + kb, base + 32768 + ldst[j]);
    }
  };

  f32x4 acc[8][4];
#pragma unroll
  for (int m = 0; m < 8; ++m)
#pragma unroll
    for (int n = 0; n < 4; ++n)
#pragma unroll
      for (int i = 0; i < 4; ++i) acc[m][n][i] = 0.0f;

  int raf[8], rbf_[4];
#pragma unroll
  for (int m = 0; m < 8; ++m) {
    const int r = wr * 128 + m * 16 + lo;
    raf[m] = r * 128 + ((hi ^ (r & 7)) << 4);
  }
#pragma unroll
  for (int n = 0; n < 4; ++n) {
    const int r = wc * 64 + n * 16 + lo;
    rbf_[n] = r * 128 + ((hi ^ (r & 7)) << 4);
  }

  auto compute = [&](int slot) {
    const char* Ac = lds + slot * 65536;
    const char* Bc = Ac + 32768;
#pragma unroll
    for (int kh = 0; kh < 2; ++kh) {
      const int kx = kh * 64;
      f16x8 af[8], bfr[4];
#pragma unroll
      for (int m = 0; m < 8; ++m)
        af[m] = *reinterpret_cast<const f16x8*>(Ac + (raf[m] ^ kx));
#pragma unroll
      for (int n = 0; n < 4; ++n)
        bfr[n] = *reinterpret_cast<const f16x8*>(Bc + (rbf_[n] ^ kx));
      __builtin_amdgcn_s_setprio(1);
#pragma unroll
      for (int m = 0; m < 8; ++m)
#pragma unroll
        for (int n = 0; n < 4; ++n)
          acc[m][n] = __builtin_amdgcn_mfma_f32_16x16x32_f16(
              af[m], bfr[n], acc[m][n], 0, 0, 0);
      __builtin_amdgcn_s_setprio(0);
      __builtin_amdgcn_sched_barrier(0);
    }
  };

  stage(0, 0);
  for (int it = 0; it < NIT; ++it) {
    asm volatile("s_waitcnt vmcnt(0) lgkmcnt(0)" ::: "memory");
    __builtin_amdgcn_sched_barrier(0);
    __builtin_amdgcn_s_barrier();
    if (it + 1 < NIT) stage(it + 1, (it + 1) & 1);
    compute(it & 1);
  }

  if constexpr (SCORES) {
    _Float16* Cb = Ch + (size_t)b * Mc * Nc;
#pragma unroll
    for (int n = 0; n < 4; ++n) {
      const int col = n0 + wc * 64 + n * 16 + lo;
#pragma unroll
      for (int m = 0; m < 8; ++m) {
        const int r0 = m0 + wr * 128 + m * 16 + hi * 4;
#pragma unroll
        for (int i = 0; i < 4; ++i)
          Cb[(size_t)(r0 + i) * Nc + col] = (_Float16)acc[m][n][i];
      }
    }
  } else {
    float* Cb = Cf + (size_t)b * Mc * Nc;
#pragma unroll
    for (int n = 0; n < 4; ++n) {
      const int col = n0 + wc * 64 + n * 16 + lo;
#pragma unroll
      for (int m = 0; m < 8; ++m) {
        const int r0 = m0 + wr * 128 + m * 16 + hi * 4;
#pragma unroll
        for (int i = 0; i < 4; ++i)
          Cb[(size_t)(r0 + i) * Nc + col] = acc[m][n][i];
      }
    }
  }
}

// ---------------------------------------------------------------- compact PV
// Same verified skeleton; A = Whc packed rows (runtime stride KA = kcpad[b]),
// B = VTc (stride 2048, first KA cols valid), runtime NIT = KA/64 (~half).
__global__ __launch_bounds__(512, 2) void fgemm_pv(
    const _Float16* __restrict__ Whc, const _Float16* __restrict__ VTc,
    float* __restrict__ Cf, const int* __restrict__ kcp) {
  constexpr int Mc = 2048, Nc = 1024;
  constexpr int GX = 8, GY = 4;
  constexpr int CPX = B_ * GX * GY / 8;

  extern __shared__ char lds[];

  const int t = threadIdx.x;
  const int lane = t & 63;
  const int wid = t >> 6;
  const int wr = wid >> 2, wc = wid & 3;
  const int lo = lane & 15, hi = lane >> 4;

  const int id = blockIdx.x;
  const int swz = (id & 7) * CPX + (id >> 3);
  const int b = swz / (GX * GY);
  const int rem = swz % (GX * GY);
  const int m0 = (rem / GY) * 256, n0 = (rem % GY) * 256;

  const int kc = kcp[b];
  const int KA = (kc + 63) & ~63;  // packed A row stride, multiple of 64
  const int NIT = KA >> 6;         // >= 1

  const _Float16* Ab = Whc + (size_t)b * 2048 * 2048;  // rows stride KA
  const _Float16* Bb = VTc + (size_t)b * Nc * KL_;     // rows stride 2048

  int aoff[4], boff[4], ldst[4];
#pragma unroll
  for (int j = 0; j < 4; ++j) {
    const int row = j * 64 + wid * 8 + (lane >> 3);
    const int cg = (lane & 7) ^ (lane >> 3);
    aoff[j] = (m0 + row) * KA + cg * 8;
    boff[j] = (n0 + row) * KL_ + cg * 8;
    ldst[j] = j * 8192 + wid * 1024;
  }

  auto stage = [&](int it, int slot) {
    char* base = lds + slot * 65536;
    const int kb = it * 64;
#pragma unroll
    for (int j = 0; j < 4; ++j) {
      async16(Ab + aoff[j] + kb, base + ldst[j]);
      async16(Bb + boff[j] + kb, base + 32768 + ldst[j]);
    }
  };

  f32x4 acc[8][4];
#pragma unroll
  for (int m = 0; m < 8; ++m)
#pragma unroll
    for (int n = 0; n < 4; ++n)
#pragma unroll
      for (int i = 0; i < 4; ++i) acc[m][n][i] = 0.0f;

  int raf[8], rbf_[4];
#pragma unroll
  for (int m = 0; m < 8; ++m) {
    const int r = wr * 128 + m * 16 + lo;
    raf[m] = r * 128 + ((hi ^ (r & 7)) << 4);
  }
#pragma unroll
  for (int n = 0; n < 4; ++n) {
    const int r = wc * 64 + n * 16 + lo;
    rbf_[n] = r * 128 + ((hi ^ (r & 7)) << 4);
  }

  auto compute = [&](int slot) {
    const char* Ac = lds + slot * 65536;
    const char* Bc = Ac + 32768;
#pragma unroll
    for (int kh = 0; kh < 2; ++kh) {
      const int kx = kh * 64;
      f16x8 af[8], bfr[4];
#pragma unroll
      for (int m = 0; m < 8; ++m)
        af[m] = *reinterpret_cast<const f16x8*>(Ac + (raf[m] ^ kx));
#pragma unroll
      for (int n = 0; n < 4; ++n)
        bfr[n] = *reinterpret_cast<const f16x8*>(Bc + (rbf_[n] ^ kx));
      __builtin_amdgcn_s_setprio(1);
#pragma unroll
      for (int m = 0; m < 8; ++m)
#pragma unroll
        for (int n = 0; n < 4; ++n)
          acc[m][n] = __builtin_amdgcn_mfma_f32_16x16x32_f16(
              af[m], bfr[n], acc[m][n], 0, 0, 0);
      __builtin_amdgcn_s_setprio(0);
      __builtin_amdgcn_sched_barrier(0);
    }
  };

  stage(0, 0);
  for (int it = 0; it < NIT; ++it) {
    asm volatile("s_waitcnt vmcnt(0) lgkmcnt(0)" ::: "memory");
    __builtin_amdgcn_sched_barrier(0);
    __builtin_amdgcn_s_barrier();
    if (it + 1 < NIT) stage(it + 1, (it + 1) & 1);
    compute(it & 1);
  }

  float* Cb = Cf + (size_t)b * Mc * Nc;
#pragma unroll
  for (int n = 0; n < 4; ++n) {
    const int col = n0 + wc * 64 + n * 16 + lo;
#pragma unroll
    for (int m = 0; m < 8; ++m) {
      const int r0 = m0 + wr * 128 + m * 16 + hi * 4;
#pragma unroll
      for (int i = 0; i < 4; ++i)
        Cb[(size_t)(r0 + i) * Nc + col] = acc[m][n][i];
    }
  }
}

// ---------------------------------------------------------------- row softmax
// One wave per row. COMPACT: Wh is the packed Whc (stride kcpad[b]); kept
// values scattered to pos[k], tail [kc,kcpad) zeroed. Else dense Wh (r11).
template <bool COMPACT>
__global__ __launch_bounds__(256) void softmax_k(
    const _Float16* __restrict__ Sh, float* __restrict__ W,
    _Float16* __restrict__ Wh, const float* __restrict__ mask,
    const int* __restrict__ pad, const int* __restrict__ pos,
    const int* __restrict__ kcp) {
  const int row = blockIdx.x * 4 + (threadIdx.x >> 6);
  const int lane = threadIdx.x & 63;
  const int b = row >> 11, q = row & 2047;
  const f16x4* Sr = reinterpret_cast<const f16x4*>(Sh + (size_t)row * KL_);
  float4* Wr = reinterpret_cast<float4*>(W + (size_t)row * KL_);
  const float4* Mr = reinterpret_cast<const float4*>(mask + (size_t)q * KL_);
  const int4* Pr = reinterpret_cast<const int4*>(pad + (size_t)b * KL_);
  int4 pk[8];
  float4 v[8];
#pragma unroll
  for (int s = 0; s < 8; ++s) {
    f16x4 sv = Sr[s * 64 + lane];
    float4 mk = Mr[s * 64 + lane];
    int4 p = Pr[s * 64 + lane];
    pk[s] = p;
    float4 x;
    x.x = p.x ? -1e12f : (float)sv[0] + mk.x;
    x.y = p.y ? -1e12f : (float)sv[1] + mk.y;
    x.z = p.z ? -1e12f : (float)sv[2] + mk.z;
    x.w = p.w ? -1e12f : (float)sv[3] + mk.w;
    v[s] = x;
  }
  float mx = -3.402823466e38f;
#pragma unroll
  for (int s = 0; s < 8; ++s)
    mx = fmaxf(mx, fmaxf(fmaxf(v[s].x, v[s].y), fmaxf(v[s].z, v[s].w)));
#pragma unroll
  for (int off = 32; off > 0; off >>= 1) mx = fmaxf(mx, __shfl_xor(mx, off));
  float sum = 0.0f;
#pragma unroll
  for (int s = 0; s < 8; ++s) {
    v[s].x = __expf(v[s].x - mx);
    v[s].y = __expf(v[s].y - mx);
    v[s].z = __expf(v[s].z - mx);
    v[s].w = __expf(v[s].w - mx);
    sum += v[s].x + v[s].y + v[s].z + v[s].w;
  }
#pragma unroll
  for (int off = 32; off > 0; off >>= 1) sum += __shfl_xor(sum, off);
  const float inv = 1.0f / sum;

  if constexpr (COMPACT) {
    const int kc = kcp[b];
    const int kcpad = (kc + 63) & ~63;
    _Float16* Wc = Wh + (size_t)b * 2048 * 2048 + (size_t)q * kcpad;
    const int4* Po = reinterpret_cast<const int4*>(pos + (size_t)b * KL_);
#pragma unroll
    for (int s = 0; s < 8; ++s) {
      float4 o;
      o.x = v[s].x * inv;
      o.y = v[s].y * inv;
      o.z = v[s].z * inv;
      o.w = v[s].w * inv;
      Wr[s * 64 + lane] = o;  // dense fp32 W output (masked cols: exact 0)
      int4 ps = Po[s * 64 + lane];
      if (!pk[s].x) Wc[ps.x] = (_Float16)o.x;
      if (!pk[s].y) Wc[ps.y] = (_Float16)o.y;
      if (!pk[s].z) Wc[ps.z] = (_Float16)o.z;
      if (!pk[s].w) Wc[ps.w] = (_Float16)o.w;
    }
    if (kc + lane < kcpad) Wc[kc + lane] = (_Float16)0.0f;  // zero tail
  } else {
    f16x4* Whr = reinterpret_cast<f16x4*>(Wh + (size_t)row * KL_);
#pragma unroll
    for (int s = 0; s < 8; ++s) {
      float4 o;
      o.x = v[s].x * inv;
      o.y = v[s].y * inv;
      o.z = v[s].z * inv;
      o.w = v[s].w * inv;
      Wr[s * 64 + lane] = o;
      f16x4 h;
      h[0] = (_Float16)o.x;
      h[1] = (_Float16)o.y;
      h[2] = (_Float16)o.z;
      h[3] = (_Float16)o.w;
      Whr[s * 64 + lane] = h;
    }
  }
}

// ---------------------------------------------------------------- launch
extern "C" void kernel_launch(void* const* d_in, const int* in_sizes, int n_in,
                              void* d_out, int out_size, void* d_ws,
                              size_t ws_size, hipStream_t stream) {
  const float* Q = (const float*)d_in[0];
  const float* K = (const float*)d_in[1];
  const float* V = (const float*)d_in[2];
  const float* mask = (const float*)d_in[3];
  const int* pad = (const int*)d_in[4];

  float* ctx = (float*)d_out;              // [8][2048][1024] fp32 (final)
  float* W = ctx + (size_t)B_ * QL_ * D_;  // [8][2048][2048] fp32 (final)
  _Float16* Sh = (_Float16*)d_out;         // S' fp16 reuses ctx region

  const size_t MB = 1024 * 1024;
  _Float16* VT = (_Float16*)d_ws;                     // 32 MiB
  _Float16* Qh = (_Float16*)((char*)d_ws + 32 * MB);  // 32 MiB
  _Float16* Kh = (_Float16*)((char*)d_ws + 64 * MB);  // 32 MiB
  _Float16* Wh = Qh;                                  // 64 MiB, reused post-QK

  (void)hipFuncSetAttribute((const void*)fgemm_k<true>,
                            hipFuncAttributeMaxDynamicSharedMemorySize, 131072);
  (void)hipFuncSetAttribute((const void*)fgemm_k<false>,
                            hipFuncAttributeMaxDynamicSharedMemorySize, 131072);
  (void)hipFuncSetAttribute((const void*)fgemm_pv,
                            hipFuncAttributeMaxDynamicSharedMemorySize, 131072);

  const bool compact = ws_size >= 96 * MB + (1 << 17);
  if (compact) {
    int* pos = (int*)((char*)d_ws + 96 * MB);  // [8][2048] = 64 KiB
    int* kcp = pos + B_ * KL_;                 // [8]
    prep_k<<<dim3(B_), 256, 0, stream>>>(pad, pos, kcp);
    cvt2_k<<<dim3(2 * B_ * QL_ * D_ / 8 / 256), 256, 0, stream>>>(Q, K, Qh, Kh);
    vtc_k<<<dim3(KL_ / 32, D_ / 32, B_), 256, 0, stream>>>(V, VT, pad, pos);
    fgemm_k<true><<<dim3(B_ * 8 * 8), 512, 131072, stream>>>(Qh, Kh, nullptr,
                                                             Sh);
    softmax_k<true><<<dim3(B_ * QL_ / 4), 256, 0, stream>>>(Sh, W, Wh, mask,
                                                            pad, pos, kcp);
    fgemm_pv<<<dim3(B_ * 8 * 4), 512, 131072, stream>>>(Wh, VT, ctx, kcp);
  } else {
    // r11 dense fallback
    cvt2_k<<<dim3(2 * B_ * QL_ * D_ / 8 / 256), 256, 0, stream>>>(Q, K, Qh, Kh);
    vt_k<<<dim3(KL_ / 32, D_ / 32, B_), 256, 0, stream>>>(V, VT);
    fgemm_k<true><<<dim3(B_ * 8 * 8), 512, 131072, stream>>>(Qh, Kh, nullptr,
                                                             Sh);
    softmax_k<false><<<dim3(B_ * QL_ / 4), 256, 0, stream>>>(
        Sh, W, Wh, mask, pad, nullptr, nullptr);
    fgemm_k<false><<<dim3(B_ * 8 * 4), 512, 131072, stream>>>(Wh, VT, ctx,
                                                              nullptr);
  }
}